// Round 9
// baseline (140.013 us; speedup 1.0000x reference)
//
#include <hip/hip_runtime.h>
#include <stdint.h>

#define M_DIM 16384
#define N_DIM 1024
#define K_DIM 1024

#define BM 128
#define BN 128
#define BK 64
#define NKT (K_DIM / BK)          // 16 K-steps
#define TILE_BYTES (BM * BK)      // 8192 B per (tile, K-step)

using i32x4 = __attribute__((ext_vector_type(4))) int;

__device__ __forceinline__ int pack4(int4 v) {
    return (v.x & 0xFF) | ((v.y & 0xFF) << 8) | ((v.z & 0xFF) << 16) | ((v.w & 0xFF) << 24);
}

// Swizzle: within each row's 64B (4 slots of 16B), canonical slot sigma is
// stored at s = sigma ^ ((row>>1)&3). Involution, within one 64B line ->
// global coalescing unaffected; kills the 8-way ds_read_b128 conflict.
// (R8 verified: SQ_LDS_BANK_CONFLICT == 0.)

// -------- pack x: int32 [M,K] -> swizzled-tiled i8 xqT[mtile][kt][512*16B] --------
__global__ __launch_bounds__(256) void pack_x_kernel(const int* __restrict__ X,
                                                     int8_t* __restrict__ xqT) {
    int mtile = blockIdx.x >> 4;
    int kt = blockIdx.x & 15;
    int8_t* outT = xqT + (size_t)blockIdx.x * TILE_BYTES;
    int tid = threadIdx.x;
#pragma unroll
    for (int i = 0; i < 2; ++i) {
        int c = i * 256 + tid;          // input chunk: row = c>>2, sigma = c&3
        int row = c >> 2;
        int sig = c & 3;
        const int* src = X + ((size_t)(mtile * BM + row)) * K_DIM + kt * BK + sig * 16;
        int4 p;
        p.x = pack4(*(const int4*)(src + 0));
        p.y = pack4(*(const int4*)(src + 4));
        p.z = pack4(*(const int4*)(src + 8));
        p.w = pack4(*(const int4*)(src + 12));
        int s = sig ^ ((row >> 1) & 3);           // swizzled slot
        *(int4*)(outT + ((size_t)row * 4 + s) * 16) = p;
    }
}

// ---- pack w + corr: wqT[ntile][kt][512*16B] swizzled; corr[n] = bias - 3*colsum ----
__global__ __launch_bounds__(256) void pack_w_corr_kernel(const int* __restrict__ w,
                                                          const int* __restrict__ bias,
                                                          int8_t* __restrict__ wqT,
                                                          int* __restrict__ corr) {
    int n = blockIdx.x;
    int t = threadIdx.x;
    int4 v = ((const int4*)(w + (size_t)n * K_DIM))[t];
    int pk = pack4(v);
    int kt = t >> 4;                 // 64 ints per kt
    int sig = (t >> 2) & 3;          // canonical 16B slot within the row's 64B
    int d = t & 3;                   // dword within slot
    int rowin = n & 127;
    int ntile = n >> 7;
    int s = sig ^ ((rowin >> 1) & 3);
    ((int*)(wqT + ((size_t)(ntile * NKT + kt)) * TILE_BYTES))[(rowin * 4 + s) * 4 + d] = pk;

    int sum = v.x + v.y + v.z + v.w;
#pragma unroll
    for (int m = 1; m < 64; m <<= 1) sum += __shfl_xor(sum, m);
    __shared__ int partial[4];
    if ((t & 63) == 0) partial[t >> 6] = sum;
    __syncthreads();
    if (t == 0)
        corr[n] = bias[n] - 3 * (partial[0] + partial[1] + partial[2] + partial[3]);
}

// ------------- GEMM: double-buffered LDS, counted vmcnt, raw barriers -------------
// 128x128 tile, BK=64, 4 waves (2x2 of 64x64), mfma_i32_16x16x64_i8.
// Per K-step: issue next tile's 4 global_load_lds, s_waitcnt vmcnt(4) (cur
// tile's loads done, next stays in flight ACROSS the barrier - T4), raw
// s_barrier, ds_read+MFMA, s_barrier. Fully unrolled so vmcnt N is literal.
__global__ __launch_bounds__(256) void gemm_kernel(const int8_t* __restrict__ xqT,
                                                   const int8_t* __restrict__ wqT,
                                                   const int* __restrict__ corr,
                                                   int* __restrict__ out) {
    __shared__ int8_t Asm[2][TILE_BYTES];
    __shared__ int8_t Bsm[2][TILE_BYTES];

    int bid = blockIdx.x;
    // XCD-bijective swizzle (nwg=1024 % 8 == 0).
    int swz = (bid & 7) * 128 + (bid >> 3);
    int mtile = swz >> 3;    // 0..127
    int ntile = swz & 7;     // 0..7
    int n0 = ntile * BN;

    int tid = threadIdx.x;
    int lane = tid & 63;
    int wave = tid >> 6;
    int wm = wave >> 1;
    int wn = wave & 1;
    int r16 = lane & 15;
    int krow = lane >> 4;                 // canonical k-slot
    int slot = krow ^ ((r16 >> 1) & 3);   // swizzled LDS slot

    i32x4 acc[4][4];
#pragma unroll
    for (int i = 0; i < 4; ++i)
#pragma unroll
        for (int j = 0; j < 4; ++j)
            acc[i][j] = (i32x4){0, 0, 0, 0};

    const int8_t* Abase = xqT + (size_t)mtile * NKT * TILE_BYTES;
    const int8_t* Bbase = wqT + (size_t)ntile * NKT * TILE_BYTES;

    // 4 global_load_lds per thread per K-step (2 A + 2 B), sequential 16B.
#define STAGE(buf, kt)                                                                     \
    {                                                                                      \
        const int8_t* Ag = Abase + (size_t)(kt) * TILE_BYTES;                              \
        const int8_t* Bg = Bbase + (size_t)(kt) * TILE_BYTES;                              \
        _Pragma("unroll") for (int i = 0; i < 2; ++i) {                                    \
            int f = i * 256 + tid;                                                         \
            __builtin_amdgcn_global_load_lds(                                              \
                (const __attribute__((address_space(1))) unsigned int*)(Ag + (size_t)f * 16), \
                (__attribute__((address_space(3))) unsigned int*)(&Asm[buf][0] + f * 16),  \
                16, 0, 0);                                                                 \
        }                                                                                  \
        _Pragma("unroll") for (int i = 0; i < 2; ++i) {                                    \
            int f = i * 256 + tid;                                                         \
            __builtin_amdgcn_global_load_lds(                                              \
                (const __attribute__((address_space(1))) unsigned int*)(Bg + (size_t)f * 16), \
                (__attribute__((address_space(3))) unsigned int*)(&Bsm[buf][0] + f * 16),  \
                16, 0, 0);                                                                 \
        }                                                                                  \
    }

    STAGE(0, 0);

#pragma unroll
    for (int kt = 0; kt < NKT; ++kt) {
        const int cur = kt & 1;
        if (kt < NKT - 1) {
            STAGE(cur ^ 1, kt + 1);                       // issue-early (prev barrier
                                                          // guarantees buf free)
            asm volatile("s_waitcnt vmcnt(4)" ::: "memory");   // cur done, next in flight
        } else {
            asm volatile("s_waitcnt vmcnt(0)" ::: "memory");
        }
        __builtin_amdgcn_s_barrier();                     // cur buf published

        i32x4 afr[4], bfr[4];
#pragma unroll
        for (int i = 0; i < 4; ++i) {
            afr[i] = *(const i32x4*)(&Asm[cur][0] + (size_t)(wm * 64 + i * 16 + r16) * 64 + slot * 16);
            bfr[i] = *(const i32x4*)(&Bsm[cur][0] + (size_t)(wn * 64 + i * 16 + r16) * 64 + slot * 16);
        }
#pragma unroll
        for (int i = 0; i < 4; ++i)
#pragma unroll
            for (int j = 0; j < 4; ++j)
                acc[i][j] = __builtin_amdgcn_mfma_i32_16x16x64_i8(afr[i], bfr[j], acc[i][j], 0, 0, 0);

        if (kt < NKT - 1) __builtin_amdgcn_s_barrier();   // all reads of cur done before
                                                          // it's restaged next step
    }
#undef STAGE

    // Epilogue: C/D layout col = lane&15, row = (lane>>4)*4 + reg.
    // j innermost: wave covers a contiguous 256B row segment temporally
    // adjacent -> full 128B-line HBM writes (R8 showed 1.46x write amp).
    int m0 = mtile * BM;
    int col16 = lane & 15;
    int rbase = (lane >> 4) * 4;
    int cr[4];
#pragma unroll
    for (int j = 0; j < 4; ++j) cr[j] = corr[n0 + wn * 64 + j * 16 + col16];
#pragma unroll
    for (int i = 0; i < 4; ++i) {
        int rrow = m0 + wm * 64 + i * 16 + rbase;
#pragma unroll
        for (int r = 0; r < 4; ++r) {
            size_t rowoff = (size_t)(rrow + r) * N_DIM;
#pragma unroll
            for (int j = 0; j < 4; ++j) {
                int t = acc[i][j][r] + cr[j];
                int res = ((t * 10) >> 10) - 5;       // floor((acc*10)/1024) + OUTPUT_ZP
                res = res < -128 ? -128 : (res > 127 ? 127 : res);
                out[rowoff + n0 + wn * 64 + j * 16 + col16] = res;
            }
        }
    }
}

extern "C" void kernel_launch(void* const* d_in, const int* in_sizes, int n_in,
                              void* d_out, int out_size, void* d_ws, size_t ws_size,
                              hipStream_t stream) {
    (void)in_sizes; (void)n_in; (void)out_size; (void)ws_size;
    const int* x    = (const int*)d_in[0];
    const int* w    = (const int*)d_in[1];
    const int* bias = (const int*)d_in[2];
    int* out = (int*)d_out;

    int8_t* xqT = (int8_t*)d_ws;                               // 16 MiB (tiled+swizzled)
    int8_t* wqT = xqT + (size_t)M_DIM * K_DIM;                 // 1 MiB (tiled+swizzled)
    int* corr   = (int*)(wqT + (size_t)N_DIM * K_DIM);         // 4 KiB

    pack_x_kernel<<<(M_DIM / BM) * NKT, 256, 0, stream>>>(x, xqT);
    pack_w_corr_kernel<<<N_DIM, 256, 0, stream>>>(w, bias, wqT, corr);
    gemm_kernel<<<(M_DIM / BM) * (N_DIM / BN), 256, 0, stream>>>(xqT, wqT, corr, out);
}

// Round 10
// 138.117 us; speedup vs baseline: 1.0137x; 1.0137x over previous
//
#include <hip/hip_runtime.h>
#include <stdint.h>

#define M_DIM 16384
#define N_DIM 1024
#define K_DIM 1024

#define BM 128
#define BN 128
#define BK 64
#define NKT (K_DIM / BK)          // 16 K-steps
#define TILE_BYTES (BM * BK)      // 8192 B per (tile, K-step)

using i32x4 = __attribute__((ext_vector_type(4))) int;

__device__ __forceinline__ int pack4(int4 v) {
    return (v.x & 0xFF) | ((v.y & 0xFF) << 8) | ((v.z & 0xFF) << 16) | ((v.w & 0xFF) << 24);
}

// Swizzle: within each row's 64B (4 slots of 16B), canonical slot sigma is
// stored at s = sigma ^ ((row>>1)&3). Involution, within one 64B line ->
// global coalescing unaffected; kills the 8-way ds_read_b128 conflict.
// (R8 verified: SQ_LDS_BANK_CONFLICT == 0.)

// -------- pack x: int32 [M,K] -> swizzled-tiled i8 xqT[mtile][kt][512*16B] --------
__global__ __launch_bounds__(256) void pack_x_kernel(const int* __restrict__ X,
                                                     int8_t* __restrict__ xqT) {
    int mtile = blockIdx.x >> 4;
    int kt = blockIdx.x & 15;
    int8_t* outT = xqT + (size_t)blockIdx.x * TILE_BYTES;
    int tid = threadIdx.x;
#pragma unroll
    for (int i = 0; i < 2; ++i) {
        int c = i * 256 + tid;          // input chunk: row = c>>2, sigma = c&3
        int row = c >> 2;
        int sig = c & 3;
        const int* src = X + ((size_t)(mtile * BM + row)) * K_DIM + kt * BK + sig * 16;
        int4 p;
        p.x = pack4(*(const int4*)(src + 0));
        p.y = pack4(*(const int4*)(src + 4));
        p.z = pack4(*(const int4*)(src + 8));
        p.w = pack4(*(const int4*)(src + 12));
        int s = sig ^ ((row >> 1) & 3);           // swizzled slot
        *(int4*)(outT + ((size_t)row * 4 + s) * 16) = p;
    }
}

// ---- pack w + corr: wqT[ntile][kt][512*16B] swizzled; corr[n] = bias - 3*colsum ----
__global__ __launch_bounds__(256) void pack_w_corr_kernel(const int* __restrict__ w,
                                                          const int* __restrict__ bias,
                                                          int8_t* __restrict__ wqT,
                                                          int* __restrict__ corr) {
    int n = blockIdx.x;
    int t = threadIdx.x;
    int4 v = ((const int4*)(w + (size_t)n * K_DIM))[t];
    int pk = pack4(v);
    int kt = t >> 4;                 // 64 ints per kt
    int sig = (t >> 2) & 3;          // canonical 16B slot within the row's 64B
    int d = t & 3;                   // dword within slot
    int rowin = n & 127;
    int ntile = n >> 7;
    int s = sig ^ ((rowin >> 1) & 3);
    ((int*)(wqT + ((size_t)(ntile * NKT + kt)) * TILE_BYTES))[(rowin * 4 + s) * 4 + d] = pk;

    int sum = v.x + v.y + v.z + v.w;
#pragma unroll
    for (int m = 1; m < 64; m <<= 1) sum += __shfl_xor(sum, m);
    __shared__ int partial[4];
    if ((t & 63) == 0) partial[t >> 6] = sum;
    __syncthreads();
    if (t == 0)
        corr[n] = bias[n] - 3 * (partial[0] + partial[1] + partial[2] + partial[3]);
}

// ------------- GEMM: TRIPLE-buffered LDS, depth-2 counted vmcnt -------------
// 128x128 tile, BK=64, 4 waves (2x2 of 64x64), mfma_i32_16x16x64_i8.
// Steady state: tiles kt+1 and kt+2 in flight (8 loads) while computing kt;
// s_waitcnt vmcnt(8) -> two compute phases (~400-500cy) cover L3 latency.
__global__ __launch_bounds__(256) void gemm_kernel(const int8_t* __restrict__ xqT,
                                                   const int8_t* __restrict__ wqT,
                                                   const int* __restrict__ corr,
                                                   int* __restrict__ out) {
    __shared__ int8_t Asm[3][TILE_BYTES];
    __shared__ int8_t Bsm[3][TILE_BYTES];

    int bid = blockIdx.x;
    // XCD-bijective swizzle (nwg=1024 % 8 == 0).
    int swz = (bid & 7) * 128 + (bid >> 3);
    int mtile = swz >> 3;    // 0..127
    int ntile = swz & 7;     // 0..7
    int n0 = ntile * BN;

    int tid = threadIdx.x;
    int lane = tid & 63;
    int wave = tid >> 6;
    int wm = wave >> 1;
    int wn = wave & 1;
    int r16 = lane & 15;
    int krow = lane >> 4;                 // canonical k-slot
    int slot = krow ^ ((r16 >> 1) & 3);   // swizzled LDS slot

    i32x4 acc[4][4];
#pragma unroll
    for (int i = 0; i < 4; ++i)
#pragma unroll
        for (int j = 0; j < 4; ++j)
            acc[i][j] = (i32x4){0, 0, 0, 0};

    const int8_t* Abase = xqT + (size_t)mtile * NKT * TILE_BYTES;
    const int8_t* Bbase = wqT + (size_t)ntile * NKT * TILE_BYTES;

    // 4 global_load_lds per thread per K-step (2 A + 2 B), sequential 16B.
#define STAGE(buf, kt)                                                                     \
    {                                                                                      \
        const int8_t* Ag = Abase + (size_t)(kt) * TILE_BYTES;                              \
        const int8_t* Bg = Bbase + (size_t)(kt) * TILE_BYTES;                              \
        _Pragma("unroll") for (int i = 0; i < 2; ++i) {                                    \
            int f = i * 256 + tid;                                                         \
            __builtin_amdgcn_global_load_lds(                                              \
                (const __attribute__((address_space(1))) unsigned int*)(Ag + (size_t)f * 16), \
                (__attribute__((address_space(3))) unsigned int*)(&Asm[buf][0] + f * 16),  \
                16, 0, 0);                                                                 \
        }                                                                                  \
        _Pragma("unroll") for (int i = 0; i < 2; ++i) {                                    \
            int f = i * 256 + tid;                                                         \
            __builtin_amdgcn_global_load_lds(                                              \
                (const __attribute__((address_space(1))) unsigned int*)(Bg + (size_t)f * 16), \
                (__attribute__((address_space(3))) unsigned int*)(&Bsm[buf][0] + f * 16),  \
                16, 0, 0);                                                                 \
        }                                                                                  \
    }

    STAGE(0, 0);
    STAGE(1, 1);

#pragma unroll
    for (int kt = 0; kt < NKT; ++kt) {
        const int cur = kt % 3;
        if (kt < NKT - 2) {
            STAGE((kt + 2) % 3, kt + 2);   // buf (kt+2)%3 == (kt-1)%3, consumed at
                                           // step kt-1 whose end-barrier precedes
                                           // this in program order
            asm volatile("s_waitcnt vmcnt(8)" ::: "memory");   // kt done; kt+1,kt+2 in flight
        } else if (kt == NKT - 2) {
            asm volatile("s_waitcnt vmcnt(4)" ::: "memory");   // kt done; kt+1 in flight
        } else {
            asm volatile("s_waitcnt vmcnt(0)" ::: "memory");
        }
        __builtin_amdgcn_s_barrier();      // cur buf published to all waves

        i32x4 afr[4], bfr[4];
#pragma unroll
        for (int i = 0; i < 4; ++i) {
            afr[i] = *(const i32x4*)(&Asm[cur][0] + (size_t)(wm * 64 + i * 16 + r16) * 64 + slot * 16);
            bfr[i] = *(const i32x4*)(&Bsm[cur][0] + (size_t)(wn * 64 + i * 16 + r16) * 64 + slot * 16);
        }
#pragma unroll
        for (int i = 0; i < 4; ++i)
#pragma unroll
            for (int j = 0; j < 4; ++j)
                acc[i][j] = __builtin_amdgcn_mfma_i32_16x16x64_i8(afr[i], bfr[j], acc[i][j], 0, 0, 0);

        if (kt < NKT - 1) __builtin_amdgcn_s_barrier();   // reads of cur done before
                                                          // it is restaged at kt+1
    }
#undef STAGE

    // Epilogue: C/D layout col = lane&15, row = (lane>>4)*4 + reg.
    // j innermost: each row's 256B segment written temporally adjacent.
    int m0 = mtile * BM;
    int col16 = lane & 15;
    int rbase = (lane >> 4) * 4;
    int cr[4];
#pragma unroll
    for (int j = 0; j < 4; ++j) cr[j] = corr[n0 + wn * 64 + j * 16 + col16];
#pragma unroll
    for (int i = 0; i < 4; ++i) {
        int rrow = m0 + wm * 64 + i * 16 + rbase;
#pragma unroll
        for (int r = 0; r < 4; ++r) {
            size_t rowoff = (size_t)(rrow + r) * N_DIM;
#pragma unroll
            for (int j = 0; j < 4; ++j) {
                int t = acc[i][j][r] + cr[j];
                int res = ((t * 10) >> 10) - 5;       // floor((acc*10)/1024) + OUTPUT_ZP
                res = res < -128 ? -128 : (res > 127 ? 127 : res);
                out[rowoff + n0 + wn * 64 + j * 16 + col16] = res;
            }
        }
    }
}

extern "C" void kernel_launch(void* const* d_in, const int* in_sizes, int n_in,
                              void* d_out, int out_size, void* d_ws, size_t ws_size,
                              hipStream_t stream) {
    (void)in_sizes; (void)n_in; (void)out_size; (void)ws_size;
    const int* x    = (const int*)d_in[0];
    const int* w    = (const int*)d_in[1];
    const int* bias = (const int*)d_in[2];
    int* out = (int*)d_out;

    int8_t* xqT = (int8_t*)d_ws;                               // 16 MiB (tiled+swizzled)
    int8_t* wqT = xqT + (size_t)M_DIM * K_DIM;                 // 1 MiB (tiled+swizzled)
    int* corr   = (int*)(wqT + (size_t)N_DIM * K_DIM);         // 4 KiB

    pack_x_kernel<<<(M_DIM / BM) * NKT, 256, 0, stream>>>(x, xqT);
    pack_w_corr_kernel<<<N_DIM, 256, 0, stream>>>(w, bias, wqT, corr);
    gemm_kernel<<<(M_DIM / BM) * (N_DIM / BN), 256, 0, stream>>>(xqT, wqT, corr, out);
}